// Round 3
// baseline (417.136 us; speedup 1.0000x reference)
//
#include <hip/hip_runtime.h>
#include <hip/hip_bf16.h>
#include <stdint.h>

// Problem constants (B=32, T=512, C=16, F=256, O=256)
#define R_TOTAL 16384   // B*T rows
#define F_DIM 256
#define C_DIM 16
#define O_DIM 256
#define K_DIM 768       // 3*F
#define ROWS_PB 16      // rows per block (fused kernel)
#define MIX_STRIDE 776  // 768 + 8 pad (bf16) -> lane stride 388 dwords, %32==4 (2-way, free)

using bf16x8 = __attribute__((ext_vector_type(8))) short;
using f32x4  = __attribute__((ext_vector_type(4))) float;

// RNE float->bf16 (inputs finite; no NaN path needed)
__device__ __forceinline__ unsigned short f2bf(float x) {
    union { float f; unsigned u; } a; a.f = x;
    unsigned r = a.u + 0x7FFFu + ((a.u >> 16) & 1u);
    return (unsigned short)(r >> 16);
}

// ---------------------------------------------------------------------------
// Kernel 1: weights -> concatenated transposed bf16 Wt[n=256][k=768]
// k blocks: 0:w_t, 1:w_r, 2:w_l (reference stacks [w_t, w_r, w_l]).
// Tiny (384 KB out); stays L2-resident for the fused kernel's B-frag loads.
// ---------------------------------------------------------------------------
__global__ __launch_bounds__(256) void wconv_kernel(
    const float* __restrict__ w_t, const float* __restrict__ w_l,
    const float* __restrict__ w_r, unsigned short* __restrict__ Wt)
{
    const int n = blockIdx.x;    // 0..255 output col
    const int t = threadIdx.x;   // 0..255 k within a 256-block
    unsigned short* dst = Wt + (size_t)n * K_DIM;
    dst[t]       = f2bf(w_t[(size_t)t * O_DIM + n]);
    dst[256 + t] = f2bf(w_r[(size_t)t * O_DIM + n]);
    dst[512 + t] = f2bf(w_l[(size_t)t * O_DIM + n]);
}

// ---------------------------------------------------------------------------
// Kernel 2 (fused): per-row coefficients + child mixing -> LDS, then MFMA
// GEMM against L2-resident Wt, bias + leaky_relu epilogue.
// Block = 16 rows, 256 threads (4 waves); wave w mixes rows w*4..w*4+3 and
// owns output cols [w*64, w*64+64). No barriers inside the K-loop.
// LDS ~25 KB -> ~5 blocks/CU resident; 1024 blocks -> deep stage overlap.
// ---------------------------------------------------------------------------
__global__ __launch_bounds__(256) void fused_kernel(
    const float* __restrict__ nodes,      // [R,256]
    const float* __restrict__ cv,         // [R,16,256]
    const int*   __restrict__ children,   // [R,16]
    const unsigned short* __restrict__ Wt,// [256,768] bf16
    const float* __restrict__ conv,       // [256]
    float* __restrict__ out)              // [R,256]
{
    __shared__ unsigned short mixed[ROWS_PB * MIX_STRIDE];  // ~24.3 KB

    const int tid  = threadIdx.x;
    const int lane = tid & 63;
    const int wave = tid >> 6;
    const int row0 = blockIdx.x * ROWS_PB;

    // --- coefficients: one ballot covers this wave's 4 rows ---
    // lane -> (row j = lane>>4, child i = lane&15); children[row0w*16 + lane]
    const int row0w = row0 + wave * 4;
    const int chv = children[(size_t)row0w * C_DIM + lane];
    const unsigned long long bal = __ballot(chv != 0);

    // --- stage 1: mix children vectors -> mixed[16][768] bf16 in LDS ---
#pragma unroll
    for (int j = 0; j < 4; ++j) {
        const int row = row0w + j;
        const unsigned mask16 = (unsigned)((bal >> (16 * j)) & 0xFFFFull);
        const int ns = __popc(mask16);

        float crr[C_DIM], cll[C_DIM];
        if (ns == 1) {
            // reference "singles": c_r = 0.5 on first child slot, UNmasked
#pragma unroll
            for (int i = 0; i < C_DIM; ++i) {
                float m  = (float)((mask16 >> i) & 1u);
                float cr = (i == 0) ? 0.5f : 0.0f;
                crr[i] = cr;
                cll[i] = (1.0f - cr) * m;
            }
        } else {
            float inv = (ns > 1) ? 1.0f / (float)(ns - 1) : 0.0f;  // ns==0: masks all 0
#pragma unroll
            for (int i = 0; i < C_DIM; ++i) {
                float m  = (float)((mask16 >> i) & 1u);
                float cr = (float)i * m * inv;
                crr[i] = cr;
                cll[i] = (1.0f - cr) * m;
            }
        }

        const float4* cvp = (const float4*)(cv + (size_t)row * (C_DIM * F_DIM));
        float4 mr = make_float4(0.f, 0.f, 0.f, 0.f);
        float4 ml = make_float4(0.f, 0.f, 0.f, 0.f);
#pragma unroll
        for (int i = 0; i < C_DIM; ++i) {
            float4 v = cvp[i * 64 + lane];
            float cr = crr[i], cl = cll[i];
            mr.x = fmaf(v.x, cr, mr.x); mr.y = fmaf(v.y, cr, mr.y);
            mr.z = fmaf(v.z, cr, mr.z); mr.w = fmaf(v.w, cr, mr.w);
            ml.x = fmaf(v.x, cl, ml.x); ml.y = fmaf(v.y, cl, ml.y);
            ml.z = fmaf(v.z, cl, ml.z); ml.w = fmaf(v.w, cl, ml.w);
        }
        float4 mt = ((const float4*)(nodes + (size_t)row * F_DIM))[lane];

        ushort4 ut = { f2bf(mt.x), f2bf(mt.y), f2bf(mt.z), f2bf(mt.w) };
        ushort4 ur = { f2bf(mr.x), f2bf(mr.y), f2bf(mr.z), f2bf(mr.w) };
        ushort4 ul = { f2bf(ml.x), f2bf(ml.y), f2bf(ml.z), f2bf(ml.w) };

        ushort4* mrow = (ushort4*)&mixed[(wave * 4 + j) * MIX_STRIDE];
        mrow[lane]       = ut;   // k = 4*lane          (w_t block)
        mrow[64 + lane]  = ur;   // k = 256 + 4*lane    (w_r block)
        mrow[128 + lane] = ul;   // k = 512 + 4*lane    (w_l block)
    }
    __syncthreads();

    // --- stage 2: GEMM [16 x 768] x Wt^T -> [16 x 256], wave w: cols w*64.. ---
    // Register double-buffer: prefetch frags for k+32 before MFMA of k.
    f32x4 acc[4] = {};
    const int fr  = lane & 15;          // frag row (A: m, B: n)
    const int fkd = (lane >> 4) * 8;    // frag k element offset
    const unsigned short* bbase = Wt + (size_t)(wave * 64 + fr) * K_DIM + fkd;
    const unsigned short* abase = &mixed[fr * MIX_STRIDE + fkd];

    bf16x8 bn[4], an;
#pragma unroll
    for (int ni = 0; ni < 4; ++ni)
        bn[ni] = *(const bf16x8*)(bbase + (size_t)ni * 16 * K_DIM);
    an = *(const bf16x8*)abase;

    for (int k0 = 0; k0 < K_DIM; k0 += 32) {
        bf16x8 bc[4];
#pragma unroll
        for (int ni = 0; ni < 4; ++ni) bc[ni] = bn[ni];
        bf16x8 ac = an;
        const int kn = k0 + 32;
        if (kn < K_DIM) {
#pragma unroll
            for (int ni = 0; ni < 4; ++ni)
                bn[ni] = *(const bf16x8*)(bbase + (size_t)ni * 16 * K_DIM + kn);
            an = *(const bf16x8*)(abase + kn);
        }
#pragma unroll
        for (int ni = 0; ni < 4; ++ni)
            acc[ni] = __builtin_amdgcn_mfma_f32_16x16x32_bf16(ac, bc[ni], acc[ni], 0, 0, 0);
    }

    // --- epilogue: +conv, leaky_relu(0.01), fp32 out ---
    // C/D layout: col = lane&15, row = (lane>>4)*4 + reg   [m89/m91]
    const int cn    = lane & 15;
    const int rbase = (lane >> 4) * 4;
#pragma unroll
    for (int ni = 0; ni < 4; ++ni) {
        const int ncol = wave * 64 + ni * 16 + cn;
        const float cb = conv[ncol];
        float* op = out + (size_t)(row0 + rbase) * O_DIM + ncol;
#pragma unroll
        for (int r = 0; r < 4; ++r) {
            float v = acc[ni][r] + cb;
            op[(size_t)r * O_DIM] = (v > 0.0f) ? v : 0.01f * v;
        }
    }
}

// ---------------------------------------------------------------------------
extern "C" void kernel_launch(void* const* d_in, const int* in_sizes, int n_in,
                              void* d_out, int out_size, void* d_ws, size_t ws_size,
                              hipStream_t stream) {
    // setup_inputs order: nodes, children_vectors, w_t, w_l, w_r, conv, children
    const float* nodes    = (const float*)d_in[0];
    const float* cv       = (const float*)d_in[1];
    const float* w_t      = (const float*)d_in[2];
    const float* w_l      = (const float*)d_in[3];
    const float* w_r      = (const float*)d_in[4];
    const float* conv     = (const float*)d_in[5];
    const int*   children = (const int*)d_in[6];
    float* out = (float*)d_out;

    unsigned short* Wt = (unsigned short*)d_ws;   // 384 KB bf16

    wconv_kernel<<<dim3(O_DIM), dim3(256), 0, stream>>>(w_t, w_l, w_r, Wt);
    fused_kernel<<<dim3(R_TOTAL / ROWS_PB), dim3(256), 0, stream>>>(
        nodes, cv, children, Wt, conv, out);
}

// Round 4
// 410.914 us; speedup vs baseline: 1.0151x; 1.0151x over previous
//
#include <hip/hip_runtime.h>
#include <hip/hip_bf16.h>
#include <stdint.h>

// Problem constants (B=32, T=512, C=16, F=256, O=256)
#define R_TOTAL 16384   // B*T rows
#define F_DIM 256
#define C_DIM 16
#define O_DIM 256
#define K_DIM 768       // 3*F
#define ROWS_PB 32      // rows per block (fused kernel) — best measured (R2)
#define MIX_STRIDE 784  // 768 + 16 pad (bf16 elements)

using bf16x8 = __attribute__((ext_vector_type(8))) short;
using f32x4  = __attribute__((ext_vector_type(4))) float;

// RNE float->bf16 (inputs finite; no NaN path needed)
__device__ __forceinline__ unsigned short f2bf(float x) {
    union { float f; unsigned u; } a; a.f = x;
    unsigned r = a.u + 0x7FFFu + ((a.u >> 16) & 1u);
    return (unsigned short)(r >> 16);
}

// ---------------------------------------------------------------------------
// Kernel 1: weights -> concatenated transposed bf16 Wt[n=256][k=768]
// k blocks: 0:w_t, 1:w_r, 2:w_l (reference stacks [w_t, w_r, w_l]).
// Tiny (384 KB out); stays L2-resident for the fused kernel's B-frag loads.
// ---------------------------------------------------------------------------
__global__ __launch_bounds__(256) void wconv_kernel(
    const float* __restrict__ w_t, const float* __restrict__ w_l,
    const float* __restrict__ w_r, unsigned short* __restrict__ Wt)
{
    const int n = blockIdx.x;    // 0..255 output col
    const int t = threadIdx.x;   // 0..255 k within a 256-block
    unsigned short* dst = Wt + (size_t)n * K_DIM;
    dst[t]       = f2bf(w_t[(size_t)t * O_DIM + n]);
    dst[256 + t] = f2bf(w_r[(size_t)t * O_DIM + n]);
    dst[512 + t] = f2bf(w_l[(size_t)t * O_DIM + n]);
}

// ---------------------------------------------------------------------------
// Kernel 2 (fused): per-row coefficients (ballot, register-only) + child
// mixing -> LDS, then MFMA GEMM against L2-resident Wt, bias + leaky_relu.
// Block = 32 rows, 256 threads (4 waves); wave w mixes rows w*8..w*8+7 and
// owns output cols [w*64, w*64+64). No barriers inside the K-loop
// (A is read-only LDS after the single barrier, B comes from global/L2).
// ---------------------------------------------------------------------------
__global__ __launch_bounds__(256) void fused_kernel(
    const float* __restrict__ nodes,      // [R,256]
    const float* __restrict__ cv,         // [R,16,256]
    const int*   __restrict__ children,   // [R,16]
    const unsigned short* __restrict__ Wt,// [256,768] bf16
    const float* __restrict__ conv,       // [256]
    float* __restrict__ out)              // [R,256]
{
    __shared__ unsigned short mixed[ROWS_PB * MIX_STRIDE];  // ~49 KB

    const int tid  = threadIdx.x;
    const int lane = tid & 63;
    const int wave = tid >> 6;
    const int row0 = blockIdx.x * ROWS_PB;
    const int rw0  = row0 + wave * 8;     // this wave's first row

    // --- coefficients: two ballots cover this wave's 8 rows ---
    // ballot g: lane -> (row rw0 + g*4 + (lane>>4), child i = lane&15)
    unsigned long long bal[2];
#pragma unroll
    for (int g = 0; g < 2; ++g) {
        const int chv = children[(size_t)(rw0 + g * 4) * C_DIM + lane];
        bal[g] = __ballot(chv != 0);
    }

    // --- stage 1: mix children vectors -> mixed[32][768] bf16 in LDS ---
#pragma unroll
    for (int j = 0; j < 8; ++j) {
        const int row = rw0 + j;
        const unsigned mask16 =
            (unsigned)((bal[j >> 2] >> (16 * (j & 3))) & 0xFFFFull);
        const int ns = __popc(mask16);

        float crr[C_DIM], cll[C_DIM];
        if (ns == 1) {
            // reference "singles": c_r = 0.5 on first child slot, UNmasked
#pragma unroll
            for (int i = 0; i < C_DIM; ++i) {
                float m  = (float)((mask16 >> i) & 1u);
                float cr = (i == 0) ? 0.5f : 0.0f;
                crr[i] = cr;
                cll[i] = (1.0f - cr) * m;
            }
        } else {
            float inv = (ns > 1) ? 1.0f / (float)(ns - 1) : 0.0f;  // ns==0: masks all 0
#pragma unroll
            for (int i = 0; i < C_DIM; ++i) {
                float m  = (float)((mask16 >> i) & 1u);
                float cr = (float)i * m * inv;
                crr[i] = cr;
                cll[i] = (1.0f - cr) * m;
            }
        }

        const float4* cvp = (const float4*)(cv + (size_t)row * (C_DIM * F_DIM));
        float4 mr = make_float4(0.f, 0.f, 0.f, 0.f);
        float4 ml = make_float4(0.f, 0.f, 0.f, 0.f);
#pragma unroll
        for (int i = 0; i < C_DIM; ++i) {
            float4 v = cvp[i * 64 + lane];
            float cr = crr[i], cl = cll[i];
            mr.x = fmaf(v.x, cr, mr.x); mr.y = fmaf(v.y, cr, mr.y);
            mr.z = fmaf(v.z, cr, mr.z); mr.w = fmaf(v.w, cr, mr.w);
            ml.x = fmaf(v.x, cl, ml.x); ml.y = fmaf(v.y, cl, ml.y);
            ml.z = fmaf(v.z, cl, ml.z); ml.w = fmaf(v.w, cl, ml.w);
        }
        float4 mt = ((const float4*)(nodes + (size_t)row * F_DIM))[lane];

        ushort4 ut = { f2bf(mt.x), f2bf(mt.y), f2bf(mt.z), f2bf(mt.w) };
        ushort4 ur = { f2bf(mr.x), f2bf(mr.y), f2bf(mr.z), f2bf(mr.w) };
        ushort4 ul = { f2bf(ml.x), f2bf(ml.y), f2bf(ml.z), f2bf(ml.w) };

        ushort4* mrow = (ushort4*)&mixed[(wave * 8 + j) * MIX_STRIDE];
        mrow[lane]       = ut;   // k = 4*lane          (w_t block)
        mrow[64 + lane]  = ur;   // k = 256 + 4*lane    (w_r block)
        mrow[128 + lane] = ul;   // k = 512 + 4*lane    (w_l block)
    }
    __syncthreads();

    // --- stage 2: GEMM [32 x 768] x Wt^T -> [32 x 256], wave w: cols w*64.. ---
    f32x4 acc[2][4] = {};
    const int fr  = lane & 15;          // frag row (A: m, B: n)
    const int fkd = (lane >> 4) * 8;    // frag k element offset
    const unsigned short* bptr = Wt + (size_t)(wave * 64 + fr) * K_DIM + fkd;
    const unsigned short* aptr = &mixed[fr * MIX_STRIDE + fkd];

    for (int k0 = 0; k0 < K_DIM; k0 += 32) {
        bf16x8 bfrag[4];
#pragma unroll
        for (int ni = 0; ni < 4; ++ni)
            bfrag[ni] = *(const bf16x8*)(bptr + (size_t)ni * 16 * K_DIM + k0);
        bf16x8 afrag[2];
#pragma unroll
        for (int mi = 0; mi < 2; ++mi)
            afrag[mi] = *(const bf16x8*)(aptr + mi * 16 * MIX_STRIDE + k0);
#pragma unroll
        for (int mi = 0; mi < 2; ++mi)
#pragma unroll
            for (int ni = 0; ni < 4; ++ni)
                acc[mi][ni] = __builtin_amdgcn_mfma_f32_16x16x32_bf16(
                    afrag[mi], bfrag[ni], acc[mi][ni], 0, 0, 0);
    }

    // --- epilogue: +conv, leaky_relu(0.01), fp32 out ---
    // C/D layout: col = lane&15, row = (lane>>4)*4 + reg   [m89/m91]
    const int cn    = lane & 15;
    const int rbase = (lane >> 4) * 4;
#pragma unroll
    for (int ni = 0; ni < 4; ++ni) {
        const int ncol = wave * 64 + ni * 16 + cn;
        const float cb = conv[ncol];
#pragma unroll
        for (int mi = 0; mi < 2; ++mi) {
            const int mrow = row0 + mi * 16 + rbase;
            float* op = out + (size_t)mrow * O_DIM + ncol;
#pragma unroll
            for (int r = 0; r < 4; ++r) {
                float v = acc[mi][ni][r] + cb;
                op[(size_t)r * O_DIM] = (v > 0.0f) ? v : 0.01f * v;
            }
        }
    }
}

// ---------------------------------------------------------------------------
extern "C" void kernel_launch(void* const* d_in, const int* in_sizes, int n_in,
                              void* d_out, int out_size, void* d_ws, size_t ws_size,
                              hipStream_t stream) {
    // setup_inputs order: nodes, children_vectors, w_t, w_l, w_r, conv, children
    const float* nodes    = (const float*)d_in[0];
    const float* cv       = (const float*)d_in[1];
    const float* w_t      = (const float*)d_in[2];
    const float* w_l      = (const float*)d_in[3];
    const float* w_r      = (const float*)d_in[4];
    const float* conv     = (const float*)d_in[5];
    const int*   children = (const int*)d_in[6];
    float* out = (float*)d_out;

    unsigned short* Wt = (unsigned short*)d_ws;   // 384 KB bf16

    wconv_kernel<<<dim3(O_DIM), dim3(256), 0, stream>>>(w_t, w_l, w_r, Wt);
    fused_kernel<<<dim3(R_TOTAL / ROWS_PB), dim3(256), 0, stream>>>(
        nodes, cv, children, Wt, conv, out);
}